// Round 7
// baseline (1481.102 us; speedup 1.0000x reference)
//
#include <hip/hip_runtime.h>
#include <hip/hip_bf16.h>

#define M_N 100000
#define K_F 512
#define N_F 128
#define N_E 1600000
#define NBUK 782           // ceil(100000/128) dst-buckets of 128 nodes
#define CAP 2560           // per-bucket capacity (mean 2046, sd 45 -> +11 sigma)
#define EPB 16384          // edges per k_bin block

typedef __attribute__((ext_vector_type(8))) short bf16x8;
typedef __attribute__((ext_vector_type(4))) float f32x4;

__device__ __forceinline__ unsigned short f2bf(float f) {
  unsigned u = __float_as_uint(f);
  u += 0x7FFFu + ((u >> 16) & 1u);      // RNE
  return (unsigned short)(u >> 16);
}

__device__ __forceinline__ unsigned pkbf(float a, float b) {
  __hip_bfloat162 h = __float22bfloat162_rn(make_float2(a, b));
  return *(unsigned*)&h;                // v_cvt_pk_bf16_f32
}

__device__ __forceinline__ float bf2f(unsigned short s) {
  return __uint_as_float((unsigned)s << 16);
}

// ---------- 1) weight: f32 [512][128] -> bf16 transposed [128][512] ----------
__global__ void k_wt(const float* __restrict__ w, unsigned short* __restrict__ wtb) {
  int idx = blockIdx.x * 256 + threadIdx.x;     // 65536 total
  int k = idx >> 7, n = idx & 127;
  wtb[n * K_F + k] = f2bf(w[idx]);              // w[idx] == w[k][n]
}

// ---------- 2) GEMM: global_load_lds double-buffered, A f32 in LDS ----------
__global__ __launch_bounds__(256, 2) void k_gemm(const float* __restrict__ A,
                       const unsigned short* __restrict__ Bt,   // [128][512] bf16
                       unsigned short* __restrict__ S) {        // [M][128] bf16
  __shared__ __align__(16) float As[2][128 * 64];               // 64KB total
  const int tid = threadIdx.x;
  const int lane = tid & 63;
  const int wv = tid >> 6;
  const int lr = lane & 15, lq = lane >> 4;
  const int bm0 = blockIdx.x * 128;
  const int wrow = wv * 32;

  const unsigned short* bbase = Bt + (size_t)lr * K_F + lq * 8;

  f32x4 acc[2][8] = {};

  // prologue: stage tile 0
#pragma unroll
  for (int i = 0; i < 8; i++) {
    int idx = i * 256 + tid;
    int r = idx >> 4, c = idx & 15;
    int gr = bm0 + r; if (gr > M_N - 1) gr = M_N - 1;
    const float* src = A + (size_t)gr * K_F + 0 + (c ^ (r & 7)) * 4;
    __builtin_amdgcn_global_load_lds(
        (const __attribute__((address_space(1))) void*)src,
        (__attribute__((address_space(3))) void*)&As[0][(i * 256 + wv * 64) * 4],
        16, 0, 0);
  }
  __syncthreads();

#pragma unroll
  for (int t = 0; t < 8; t++) {
    const int cur = t & 1;
    const int k0 = t * 64;

    // B fragments for this K-tile (before STAGE: their wait won't drain it)
    bf16x8 pb[8][2];
#pragma unroll
    for (int n = 0; n < 8; n++)
#pragma unroll
      for (int ks = 0; ks < 2; ks++)
        pb[n][ks] = *(const bf16x8*)(bbase + (size_t)n * 16 * K_F + k0 + ks * 32);

    // stage tile t+1 (fire-and-forget)
    if (t < 7) {
#pragma unroll
      for (int i = 0; i < 8; i++) {
        int idx = i * 256 + tid;
        int r = idx >> 4, c = idx & 15;
        int gr = bm0 + r; if (gr > M_N - 1) gr = M_N - 1;
        const float* src = A + (size_t)gr * K_F + (k0 + 64) + (c ^ (r & 7)) * 4;
        __builtin_amdgcn_global_load_lds(
            (const __attribute__((address_space(1))) void*)src,
            (__attribute__((address_space(3))) void*)&As[cur ^ 1][(i * 256 + wv * 64) * 4],
            16, 0, 0);
      }
    }

    // compute on buf[cur]
#pragma unroll
    for (int ks = 0; ks < 2; ks++)
#pragma unroll
      for (int m = 0; m < 2; m++) {
        int R = wrow + m * 16 + lr;
        int cb = ks * 8 + lq * 2;           // 16B-chunk index (pre-swizzle)
        int sw = R & 7;
        f32x4 f0 = *(const f32x4*)&As[cur][(R * 16 + (cb ^ sw)) * 4];
        f32x4 f1 = *(const f32x4*)&As[cur][(R * 16 + ((cb + 1) ^ sw)) * 4];
        uint4 u;
        u.x = pkbf(f0[0], f0[1]);
        u.y = pkbf(f0[2], f0[3]);
        u.z = pkbf(f1[0], f1[1]);
        u.w = pkbf(f1[2], f1[3]);
        bf16x8 af = *(bf16x8*)&u;
#pragma unroll
        for (int n = 0; n < 8; n++)
          acc[m][n] = __builtin_amdgcn_mfma_f32_16x16x32_bf16(af, pb[n][ks], acc[m][n], 0, 0, 0);
      }
    __syncthreads();
  }

  // epilogue: D layout col=lane&15, row=(lane>>4)*4+j  [measured m89]
#pragma unroll
  for (int m = 0; m < 2; m++)
#pragma unroll
    for (int j = 0; j < 4; j++) {
      int gr = bm0 + wrow + m * 16 + lq * 4 + j;
      if (gr < M_N) {
#pragma unroll
        for (int n = 0; n < 8; n++)
          S[(size_t)gr * N_F + n * 16 + lr] = f2bf(acc[m][n][j]);
      }
    }
}

// ---------- 3) init bucket cursors ----------
__global__ void k_init(int* __restrict__ gcur) {
  int b = blockIdx.x * 256 + threadIdx.x;
  if (b < NBUK) gcur[b] = b * CAP;
}

// ---------- 4) bin edges by dst>>7 with per-block run reservation ----------
// All writes to a 64B ebin line come from ONE block (= one XCD L2) in
// contiguous runs -> full-line writebacks (fixes the partial-line RMW that
// made the old CSR fill ~100MB / ~850GB/s).
__global__ __launch_bounds__(512) void k_bin(const int* __restrict__ src,
                                             const int* __restrict__ dst,
                                             const float* __restrict__ w,
                                             int* __restrict__ gcur,
                                             uint2* __restrict__ ebin) {
  __shared__ int lh[NBUK];
  __shared__ int lb[NBUK];
  const int tid = threadIdx.x;
  const int e0 = blockIdx.x * EPB;
  for (int b = tid; b < NBUK; b += 512) lh[b] = 0;
  __syncthreads();
#pragma unroll
  for (int i = 0; i < 32; i++) {
    int e = e0 + i * 512 + tid;
    if (e < N_E) atomicAdd(&lh[dst[e] >> 7], 1);
  }
  __syncthreads();
  for (int b = tid; b < NBUK; b += 512) {
    int c = lh[b];
    lb[b] = c ? atomicAdd(&gcur[b], c) : 0;
    lh[b] = 0;                       // reuse as rank cursor
  }
  __syncthreads();
#pragma unroll
  for (int i = 0; i < 32; i++) {
    int e = e0 + i * 512 + tid;
    if (e < N_E) {
      int d = dst[e];
      int bk = d >> 7;
      int rank = atomicAdd(&lh[bk], 1);
      ebin[lb[bk] + rank] =
          make_uint2(((unsigned)(d & 127) << 17) | (unsigned)src[e],
                     __float_as_uint(w[e]));
    }
  }
}

// ---------- 5) bucketed SpMM: one block per 128-node bucket, LDS f32 acc ----------
__global__ __launch_bounds__(512) void k_bspmm(const unsigned short* __restrict__ S,
                                               const int* __restrict__ gcur,
                                               const uint2* __restrict__ ebin,
                                               float* __restrict__ out) {
  __shared__ __align__(16) float facc[128 * 128];   // 64KB -> 2 blocks/CU
  const int b = blockIdx.x;
  const int tid = threadIdx.x;
  const int lane = tid & 63, wv = tid >> 6;

#pragma unroll
  for (int i = 0; i < 8; i++)
    *(f32x4*)&facc[(i * 512 + tid) * 4] = (f32x4){0.f, 0.f, 0.f, 0.f};
  __syncthreads();

  const int cnt = gcur[b] - b * CAP;
  const uint2* eb = ebin + (size_t)b * CAP;

  // wave wv: 4 consecutive edges per iter (32B broadcast descriptor load),
  // rows as 2 bf16-half gathers per edge; ds_add at lane / lane+64 ->
  // bank = lane%32, 2-way alias only (free).
  for (int i = wv * 4; i < cnt; i += 32) {
    uint4 q0 = *(const uint4*)(eb + i);
    uint4 q1 = *(const uint4*)(eb + i + 2);
    const unsigned short* r0 = S + (size_t)(q0.x & 0x1FFFFu) * N_F;
    const unsigned short* r1 = S + (size_t)(q0.z & 0x1FFFFu) * N_F;
    const unsigned short* r2 = S + (size_t)(q1.x & 0x1FFFFu) * N_F;
    const unsigned short* r3 = S + (size_t)(q1.z & 0x1FFFFu) * N_F;
    unsigned short a0 = r0[lane], c0 = r0[lane + 64];
    unsigned short a1 = r1[lane], c1 = r1[lane + 64];
    unsigned short a2 = r2[lane], c2 = r2[lane + 64];
    unsigned short a3 = r3[lane], c3 = r3[lane + 64];
    float w0 = __uint_as_float(q0.y);                              // i+0 < cnt always
    float w1 = (i + 1 < cnt) ? __uint_as_float(q0.w) : 0.f;
    float w2 = (i + 2 < cnt) ? __uint_as_float(q1.y) : 0.f;
    float w3 = (i + 3 < cnt) ? __uint_as_float(q1.w) : 0.f;
    int dl0 = (q0.x >> 17) & 127, dl1 = (q0.z >> 17) & 127;
    int dl2 = (q1.x >> 17) & 127, dl3 = (q1.z >> 17) & 127;
    atomicAdd(&facc[dl0 * 128 + lane],      w0 * bf2f(a0));
    atomicAdd(&facc[dl0 * 128 + 64 + lane], w0 * bf2f(c0));
    atomicAdd(&facc[dl1 * 128 + lane],      w1 * bf2f(a1));
    atomicAdd(&facc[dl1 * 128 + 64 + lane], w1 * bf2f(c1));
    atomicAdd(&facc[dl2 * 128 + lane],      w2 * bf2f(a2));
    atomicAdd(&facc[dl2 * 128 + 64 + lane], w2 * bf2f(c2));
    atomicAdd(&facc[dl3 * 128 + lane],      w3 * bf2f(a3));
    atomicAdd(&facc[dl3 * 128 + 64 + lane], w3 * bf2f(c3));
  }
  __syncthreads();

  const int nb = b * 128;
#pragma unroll
  for (int j = 0; j < 8; j++) {
    int idx = j * 512 + tid;
    int r = idx >> 5, f = (idx & 31) * 4;
    int node = nb + r;
    if (node < M_N) {
      f32x4 v = *(const f32x4*)&facc[r * 128 + f];
      float4 o = make_float4(fmaxf(v[0], 0.f), fmaxf(v[1], 0.f),
                             fmaxf(v[2], 0.f), fmaxf(v[3], 0.f));
      *(float4*)(out + (size_t)node * N_F + f) = o;
    }
  }
}

extern "C" void kernel_launch(void* const* d_in, const int* in_sizes, int n_in,
                              void* d_out, int out_size, void* d_ws, size_t ws_size,
                              hipStream_t stream) {
  const float* features = (const float*)d_in[0];
  const float* weight   = (const float*)d_in[1];
  const int* edge_src   = (const int*)d_in[2];
  const int* edge_dst   = (const int*)d_in[3];
  const float* edge_w   = (const float*)d_in[4];
  float* out = (float*)d_out;

  // workspace layout (256B-aligned chunks)
  char* ws = (char*)d_ws;
  size_t off = 0;
  unsigned short* support = (unsigned short*)(ws + off); off += (size_t)M_N * N_F * 2;   // 25.6MB
  unsigned short* wtb     = (unsigned short*)(ws + off); off += (size_t)N_F * K_F * 2;   // 128KB
  int* gcur   = (int*)(ws + off); off += 4096;
  uint2* ebin = (uint2*)(ws + off); off += ((size_t)NBUK * CAP + 64) * 8;                // ~16MB

  k_wt<<<256, 256, 0, stream>>>(weight, wtb);
  k_gemm<<<(M_N + 127) / 128, 256, 0, stream>>>(features, wtb, support);
  k_init<<<4, 256, 0, stream>>>(gcur);
  k_bin<<<(N_E + EPB - 1) / EPB, 512, 0, stream>>>(edge_src, edge_dst, edge_w, gcur, ebin);
  k_bspmm<<<NBUK, 512, 0, stream>>>(support, gcur, ebin, out);
}

// Round 8
// 226.661 us; speedup vs baseline: 6.5344x; 6.5344x over previous
//
#include <hip/hip_runtime.h>
#include <hip/hip_bf16.h>

#define M_N 100000
#define K_F 512
#define N_F 128
#define N_E 1600000
#define NBUK 782           // ceil(100000/128) dst-buckets of 128 nodes
#define CAP 2560           // per-bucket capacity (mean 2046, sd 45 -> +11 sigma)
#define EPB 16384          // edges per k_bin block

typedef __attribute__((ext_vector_type(8))) short bf16x8;
typedef __attribute__((ext_vector_type(4))) float f32x4;

__device__ __forceinline__ unsigned short f2bf(float f) {
  unsigned u = __float_as_uint(f);
  u += 0x7FFFu + ((u >> 16) & 1u);      // RNE
  return (unsigned short)(u >> 16);
}

__device__ __forceinline__ unsigned pkbf(float a, float b) {
  __hip_bfloat162 h = __float22bfloat162_rn(make_float2(a, b));
  return *(unsigned*)&h;                // v_cvt_pk_bf16_f32
}

// ---------- 1) weight: f32 [512][128] -> bf16 transposed [128][512] ----------
__global__ void k_wt(const float* __restrict__ w, unsigned short* __restrict__ wtb) {
  int idx = blockIdx.x * 256 + threadIdx.x;     // 65536 total
  int k = idx >> 7, n = idx & 127;
  wtb[n * K_F + k] = f2bf(w[idx]);              // w[idx] == w[k][n]
}

// ---------- 2) GEMM: global_load_lds double-buffered, A f32 in LDS ----------
__global__ __launch_bounds__(256, 2) void k_gemm(const float* __restrict__ A,
                       const unsigned short* __restrict__ Bt,   // [128][512] bf16
                       unsigned short* __restrict__ S) {        // [M][128] bf16
  __shared__ __align__(16) float As[2][128 * 64];               // 64KB total
  const int tid = threadIdx.x;
  const int lane = tid & 63;
  const int wv = tid >> 6;
  const int lr = lane & 15, lq = lane >> 4;
  const int bm0 = blockIdx.x * 128;
  const int wrow = wv * 32;

  const unsigned short* bbase = Bt + (size_t)lr * K_F + lq * 8;

  f32x4 acc[2][8] = {};

  // prologue: stage tile 0
#pragma unroll
  for (int i = 0; i < 8; i++) {
    int idx = i * 256 + tid;
    int r = idx >> 4, c = idx & 15;
    int gr = bm0 + r; if (gr > M_N - 1) gr = M_N - 1;
    const float* src = A + (size_t)gr * K_F + 0 + (c ^ (r & 7)) * 4;
    __builtin_amdgcn_global_load_lds(
        (const __attribute__((address_space(1))) void*)src,
        (__attribute__((address_space(3))) void*)&As[0][(i * 256 + wv * 64) * 4],
        16, 0, 0);
  }
  __syncthreads();

#pragma unroll
  for (int t = 0; t < 8; t++) {
    const int cur = t & 1;
    const int k0 = t * 64;

    // B fragments for this K-tile (before STAGE: their wait won't drain it)
    bf16x8 pb[8][2];
#pragma unroll
    for (int n = 0; n < 8; n++)
#pragma unroll
      for (int ks = 0; ks < 2; ks++)
        pb[n][ks] = *(const bf16x8*)(bbase + (size_t)n * 16 * K_F + k0 + ks * 32);

    // stage tile t+1 (fire-and-forget)
    if (t < 7) {
#pragma unroll
      for (int i = 0; i < 8; i++) {
        int idx = i * 256 + tid;
        int r = idx >> 4, c = idx & 15;
        int gr = bm0 + r; if (gr > M_N - 1) gr = M_N - 1;
        const float* src = A + (size_t)gr * K_F + (k0 + 64) + (c ^ (r & 7)) * 4;
        __builtin_amdgcn_global_load_lds(
            (const __attribute__((address_space(1))) void*)src,
            (__attribute__((address_space(3))) void*)&As[cur ^ 1][(i * 256 + wv * 64) * 4],
            16, 0, 0);
      }
    }

    // compute on buf[cur]
#pragma unroll
    for (int ks = 0; ks < 2; ks++)
#pragma unroll
      for (int m = 0; m < 2; m++) {
        int R = wrow + m * 16 + lr;
        int cb = ks * 8 + lq * 2;           // 16B-chunk index (pre-swizzle)
        int sw = R & 7;
        f32x4 f0 = *(const f32x4*)&As[cur][(R * 16 + (cb ^ sw)) * 4];
        f32x4 f1 = *(const f32x4*)&As[cur][(R * 16 + ((cb + 1) ^ sw)) * 4];
        uint4 u;
        u.x = pkbf(f0[0], f0[1]);
        u.y = pkbf(f0[2], f0[3]);
        u.z = pkbf(f1[0], f1[1]);
        u.w = pkbf(f1[2], f1[3]);
        bf16x8 af = *(bf16x8*)&u;
#pragma unroll
        for (int n = 0; n < 8; n++)
          acc[m][n] = __builtin_amdgcn_mfma_f32_16x16x32_bf16(af, pb[n][ks], acc[m][n], 0, 0, 0);
      }
    __syncthreads();
  }

  // epilogue: D layout col=lane&15, row=(lane>>4)*4+j  [measured m89]
#pragma unroll
  for (int m = 0; m < 2; m++)
#pragma unroll
    for (int j = 0; j < 4; j++) {
      int gr = bm0 + wrow + m * 16 + lq * 4 + j;
      if (gr < M_N) {
#pragma unroll
        for (int n = 0; n < 8; n++)
          S[(size_t)gr * N_F + n * 16 + lr] = f2bf(acc[m][n][j]);
      }
    }
}

// ---------- 3) init bucket cursors ----------
__global__ void k_init(int* __restrict__ gcur) {
  int b = blockIdx.x * 256 + threadIdx.x;
  if (b < NBUK) gcur[b] = b * CAP;
}

// ---------- 4) bin edges by dst>>7 with per-block run reservation ----------
// All writes to a 64B ebin line come from ONE block in contiguous runs ->
// full-line writebacks (fixes the partial-line RMW of direct CSR scatter).
__global__ __launch_bounds__(512) void k_bin(const int* __restrict__ src,
                                             const int* __restrict__ dst,
                                             const float* __restrict__ w,
                                             int* __restrict__ gcur,
                                             uint2* __restrict__ ebin) {
  __shared__ int lh[NBUK];
  __shared__ int lb[NBUK];
  const int tid = threadIdx.x;
  const int e0 = blockIdx.x * EPB;
  for (int b = tid; b < NBUK; b += 512) lh[b] = 0;
  __syncthreads();
#pragma unroll
  for (int i = 0; i < 32; i++) {
    int e = e0 + i * 512 + tid;
    if (e < N_E) atomicAdd(&lh[dst[e] >> 7], 1);
  }
  __syncthreads();
  for (int b = tid; b < NBUK; b += 512) {
    int c = lh[b];
    lb[b] = c ? atomicAdd(&gcur[b], c) : 0;
    lh[b] = 0;                       // reuse as rank cursor
  }
  __syncthreads();
#pragma unroll
  for (int i = 0; i < 32; i++) {
    int e = e0 + i * 512 + tid;
    if (e < N_E) {
      int d = dst[e];
      int bk = d >> 7;
      int rank = atomicAdd(&lh[bk], 1);
      ebin[lb[bk] + rank] =
          make_uint2(((unsigned)(d & 127) << 17) | (unsigned)src[e],
                     __float_as_uint(w[e]));
    }
  }
}

// ---------- 5) exclusive scan of the 782 bucket counts (1 block) ----------
__global__ void k_scanB(const int* __restrict__ gcur, int* __restrict__ cbase) {
  __shared__ int sm[1024];
  int t = threadIdx.x;
  int v = (t < NBUK) ? (gcur[t] - t * CAP) : 0;
  sm[t] = v;
  __syncthreads();
  for (int off = 1; off < 1024; off <<= 1) {
    int x = sm[t];
    int a = (t >= off) ? sm[t - off] : 0;
    __syncthreads();
    sm[t] = x + a;
    __syncthreads();
  }
  if (t < NBUK) cbase[t] = sm[t] - v;
}

// ---------- 6) per-bucket counting sort -> CSR (contiguous 16KB writes) ----------
__global__ __launch_bounds__(256) void k_csr(const uint2* __restrict__ ebin,
                                             const int* __restrict__ gcur,
                                             const int* __restrict__ cbase,
                                             int2* __restrict__ eidx,
                                             int* __restrict__ rowstart) {
  __shared__ uint2 st[CAP];                 // 20KB staging
  __shared__ int hist[128], excl[129], cur[128];
  const int b = blockIdx.x;
  const int t = threadIdx.x;
  const int cnt = gcur[b] - b * CAP;
  const uint2* eb = ebin + (size_t)b * CAP;

  if (t < 128) hist[t] = 0;
  __syncthreads();
  for (int i = t; i < cnt; i += 256) {
    uint2 e = eb[i];
    st[i] = e;
    atomicAdd(&hist[(e.x >> 17) & 127], 1);   // native ds_add_u32
  }
  __syncthreads();
  // exclusive scan over 128 counters (Hillis-Steele on excl[1..128])
  if (t < 128) excl[t + 1] = hist[t];
  if (t == 0) excl[0] = 0;
  __syncthreads();
  for (int off = 1; off < 128; off <<= 1) {
    int v = 0;
    if (t < 128) {
      v = excl[t + 1];
      if (t + 1 > off) v += excl[t + 1 - off];
    }
    __syncthreads();
    if (t < 128) excl[t + 1] = v;
    __syncthreads();
  }
  const int base = cbase[b];
  if (t < 128) {
    cur[t] = excl[t];
    int node = b * 128 + t;
    if (node <= M_N) rowstart[node] = base + excl[t];  // b=781,t=32 writes rowstart[M_N]=N_E
  }
  __syncthreads();
  for (int i = t; i < cnt; i += 256) {
    uint2 e = st[i];
    int dl = (e.x >> 17) & 127;
    int r = atomicAdd(&cur[dl], 1);
    eidx[base + r] = make_int2((int)(e.x & 0x1FFFFu), (int)e.y);
  }
}

// ---------- 7) SpMM gather: wave/node, 4 groups x unroll 2 (8 gathers in flight) ----------
__device__ __forceinline__ void fma8(float* acc, float wgt, uint4 v) {
  acc[0] = fmaf(wgt, __uint_as_float(v.x << 16), acc[0]);
  acc[1] = fmaf(wgt, __uint_as_float(v.x & 0xFFFF0000u), acc[1]);
  acc[2] = fmaf(wgt, __uint_as_float(v.y << 16), acc[2]);
  acc[3] = fmaf(wgt, __uint_as_float(v.y & 0xFFFF0000u), acc[3]);
  acc[4] = fmaf(wgt, __uint_as_float(v.z << 16), acc[4]);
  acc[5] = fmaf(wgt, __uint_as_float(v.z & 0xFFFF0000u), acc[5]);
  acc[6] = fmaf(wgt, __uint_as_float(v.w << 16), acc[6]);
  acc[7] = fmaf(wgt, __uint_as_float(v.w & 0xFFFF0000u), acc[7]);
}

__global__ void k_spmm(const unsigned short* __restrict__ S,
                       const int* __restrict__ rowstart,
                       const int2* __restrict__ eidx,
                       float* __restrict__ out) {
  int wid = (blockIdx.x * 256 + threadIdx.x) >> 6;
  int lane = threadIdx.x & 63;
  if (wid >= M_N) return;
  const int g = lane >> 4;          // edge subgroup 0..3
  const int l = lane & 15;          // 16B chunk within the 256B row
  int s = rowstart[wid], e = rowstart[wid + 1];

  float acc[8] = {0.f, 0.f, 0.f, 0.f, 0.f, 0.f, 0.f, 0.f};

  int i = s + g;
  for (; i + 4 < e; i += 8) {
    int2 p0 = eidx[i];
    int2 p1 = eidx[i + 4];
    uint4 v0 = *(const uint4*)(S + (size_t)p0.x * N_F + l * 8);
    uint4 v1 = *(const uint4*)(S + (size_t)p1.x * N_F + l * 8);
    fma8(acc, __int_as_float(p0.y), v0);
    fma8(acc, __int_as_float(p1.y), v1);
  }
  if (i < e) {
    int2 p = eidx[i];
    uint4 v = *(const uint4*)(S + (size_t)p.x * N_F + l * 8);
    fma8(acc, __int_as_float(p.y), v);
  }

  // reduce across the 4 groups (lane bits 4,5) + fused ReLU
#pragma unroll
  for (int j = 0; j < 8; j++) {
    acc[j] += __shfl_xor(acc[j], 16, 64);
    acc[j] += __shfl_xor(acc[j], 32, 64);
    acc[j] = fmaxf(acc[j], 0.f);
  }

  // coalesced 512B store from 32 lanes (groups 0,1)
  if (g < 2) {
    float4 r = make_float4(acc[g * 4 + 0], acc[g * 4 + 1], acc[g * 4 + 2], acc[g * 4 + 3]);
    *(float4*)(out + (size_t)wid * N_F + l * 8 + g * 4) = r;
  }
}

extern "C" void kernel_launch(void* const* d_in, const int* in_sizes, int n_in,
                              void* d_out, int out_size, void* d_ws, size_t ws_size,
                              hipStream_t stream) {
  const float* features = (const float*)d_in[0];
  const float* weight   = (const float*)d_in[1];
  const int* edge_src   = (const int*)d_in[2];
  const int* edge_dst   = (const int*)d_in[3];
  const float* edge_w   = (const float*)d_in[4];
  float* out = (float*)d_out;

  // workspace layout (256B-aligned chunks)
  char* ws = (char*)d_ws;
  size_t off = 0;
  unsigned short* support = (unsigned short*)(ws + off); off += (size_t)M_N * N_F * 2;   // 25.6MB
  unsigned short* wtb     = (unsigned short*)(ws + off); off += (size_t)N_F * K_F * 2;   // 128KB
  int* gcur     = (int*)(ws + off); off += 4096;
  int* cbase    = (int*)(ws + off); off += 4096;
  int* rowstart = (int*)(ws + off); off += ((size_t)(M_N + 1) * 4 + 255) / 256 * 256;
  uint2* ebin   = (uint2*)(ws + off); off += ((size_t)NBUK * CAP + 64) * 8;              // ~16MB
  int2* eidx    = (int2*)(ws + off); off += (size_t)N_E * 8;                             // 12.8MB

  k_wt<<<256, 256, 0, stream>>>(weight, wtb);
  k_gemm<<<(M_N + 127) / 128, 256, 0, stream>>>(features, wtb, support);
  k_init<<<4, 256, 0, stream>>>(gcur);
  k_bin<<<(N_E + EPB - 1) / EPB, 512, 0, stream>>>(edge_src, edge_dst, edge_w, gcur, ebin);
  k_scanB<<<1, 1024, 0, stream>>>(gcur, cbase);
  k_csr<<<NBUK, 256, 0, stream>>>(ebin, gcur, cbase, eidx, rowstart);
  k_spmm<<<(M_N * 64 + 255) / 256, 256, 0, stream>>>(support, rowstart, eidx, out);
}